// Round 1
// baseline (337.608 us; speedup 1.0000x reference)
//
#include <hip/hip_runtime.h>
#include <cstddef>

#define BT    8192
#define HD    2048
#define NS    32
#define RDIM  16
#define AD    32
#define CAPP  192            // per-pair-bucket capacity; E[count]=16.5, max~35 -> never overflows
#define NPAIR (NS * NS)      // 1024 buckets, only lo<hi (496) ever used

// ---------------- workspace layout ----------------
// [0, 4096)                          int   cnt[NPAIR]
// [4096, +NPAIR*CAPP*4)              int   tok_list[NPAIR][CAPP]
// next NPAIR*CAPP*4                  float cfa_list[NPAIR][CAPP]   (coef for lo schema)
// next NPAIR*CAPP*4                  float cfb_list[NPAIR][CAPP]   (coef for hi schema)
// next 4 MB                          float UT[32][16][2048]        (U transposed)

__device__ __forceinline__ float dot4(const float4 a, const float4 b) {
    return a.x * b.x + a.y * b.y + a.z * b.z + a.w * b.w;
}
__device__ __forceinline__ void fma4(float4& o, const float a, const float4 b) {
    o.x += a * b.x; o.y += a * b.y; o.z += a * b.z; o.w += a * b.w;
}

// ---------------- prep: zero counters + transpose U -> UT[s][k][j] ----------------
__global__ __launch_bounds__(256) void k_prep(const float* __restrict__ U,
                                              int* __restrict__ cnt,
                                              float* __restrict__ UT) {
    const int bx = blockIdx.x;
    if (bx == NS * 8) {
        for (int i = threadIdx.x; i < NPAIR; i += 256) cnt[i] = 0;
        return;
    }
    const int s = bx >> 3, jc = bx & 7;
    const int j = jc * 256 + threadIdx.x;
    const float4* Up = (const float4*)(U + ((size_t)s * HD + j) * RDIM);
    const float4 a = Up[0], b = Up[1], c = Up[2], d = Up[3];
    float* Tp = UT + (size_t)s * RDIM * HD + j;
    Tp[0]       = a.x; Tp[HD]      = a.y; Tp[2*HD]   = a.z; Tp[3*HD]   = a.w;
    Tp[4*HD]    = b.x; Tp[5*HD]    = b.y; Tp[6*HD]   = b.z; Tp[7*HD]   = b.w;
    Tp[8*HD]    = c.x; Tp[9*HD]    = c.y; Tp[10*HD]  = c.z; Tp[11*HD]  = c.w;
    Tp[12*HD]   = d.x; Tp[13*HD]   = d.y; Tp[14*HD]  = d.z; Tp[15*HD]  = d.w;
}

// ---------------- router ----------------
// 1024 blocks x 8 tokens. Wave w covers schemas w*8..w*8+7 in 2 passes of 4.
// K split across 64 lanes (float4); h register-double-buffered; Wr lane-coalesced
// (L2-resident). Cross-lane butterfly reduce; one barrier; scalar tail bucketizes
// each token into its unordered (lo,hi) schema-pair list (single atomic/token).
__global__ __launch_bounds__(256) void k_router(
    const float* __restrict__ h, const float* __restrict__ Wr,
    const float* __restrict__ attr, const float* __restrict__ Wa,
    int* __restrict__ cnt, int* __restrict__ tok_list,
    float* __restrict__ cfa_list, float* __restrict__ cfb_list)
{
    __shared__ float sc_s[8][NS + 1];
    const int tid = threadIdx.x, w = tid >> 6, lane = tid & 63;
    const int t0 = blockIdx.x * 8;

    #pragma unroll 1
    for (int g = 0; g < 2; ++g) {
        const int sb = w * 8 + g * 4;
        float vals[32];
        #pragma unroll
        for (int m = 0; m < 32; ++m) vals[m] = 0.f;

        float4 hA[8], hB[8];
        #pragma unroll
        for (int t = 0; t < 8; ++t)
            hA[t] = *(const float4*)(h + (size_t)(t0 + t) * HD + lane * 4);

        #pragma unroll 1
        for (int c = 0; c < 8; c += 2) {
            #pragma unroll
            for (int t = 0; t < 8; ++t)
                hB[t] = *(const float4*)(h + (size_t)(t0 + t) * HD + (c + 1) * 256 + lane * 4);
            #pragma unroll
            for (int sl = 0; sl < 4; ++sl) {
                const float4 wv = *(const float4*)(Wr + (size_t)(sb + sl) * HD + c * 256 + lane * 4);
                #pragma unroll
                for (int t = 0; t < 8; ++t) vals[t * 4 + sl] += dot4(hA[t], wv);
            }
            if (c < 6) {
                #pragma unroll
                for (int t = 0; t < 8; ++t)
                    hA[t] = *(const float4*)(h + (size_t)(t0 + t) * HD + (c + 2) * 256 + lane * 4);
            }
            #pragma unroll
            for (int sl = 0; sl < 4; ++sl) {
                const float4 wv = *(const float4*)(Wr + (size_t)(sb + sl) * HD + (c + 1) * 256 + lane * 4);
                #pragma unroll
                for (int t = 0; t < 8; ++t) vals[t * 4 + sl] += dot4(hB[t], wv);
            }
        }

        // reduce 32 values across 64 lanes: lane bits 0..4 select value halves
        // (pair-adjacent butterfly), bit 5 round sums duplicates.
        #pragma unroll
        for (int st = 0; st < 5; ++st) {
            const int d = 1 << st;
            const bool up = (lane & d) != 0;
            const int half = 16 >> st;
            #pragma unroll
            for (int i = 0; i < half; ++i) {
                const float lo = vals[2 * i], hi = vals[2 * i + 1];
                const float keep = up ? hi : lo, send = up ? lo : hi;
                vals[i] = keep + __shfl_xor(send, d, 64);
            }
        }
        vals[0] += __shfl_xor(vals[0], 32, 64);
        if (lane < 32)
            sc_s[lane >> 2][sb + (lane & 3)] = vals[0];   // m = t*4+sl = lane&31
    }
    __syncthreads();

    if (tid < 8) {
        const int t = tid;
        float m1 = -1e30f, m2 = -1e30f;
        int i1 = 0, i2 = 0;
        #pragma unroll 1
        for (int sI = 0; sI < NS; ++sI) {   // strict > keeps lowest index on ties (lax.top_k)
            const float v = sc_s[t][sI];
            if (v > m1) { m2 = m1; i2 = i1; m1 = v; i1 = sI; }
            else if (v > m2) { m2 = v; i2 = sI; }
        }
        float Z = 0.f;
        #pragma unroll 1
        for (int sI = 0; sI < NS; ++sI) Z += __expf(sc_s[t][sI] - m1);
        const float e2  = __expf(m2 - m1);
        // g = softmax(sc)*mask renormed by (sum + 1e-8): G_i = e_i / (e1+e2 + 1e-8*Z)
        const float den = 1.f + e2 + 1e-8f * Z;
        const float G1 = 1.f / den, G2 = e2 / den;
        float d1 = 0.f, d2 = 0.f;
        #pragma unroll 1
        for (int d = 0; d < AD; ++d) {
            d1 += attr[i1 * AD + d] * Wa[d];
            d2 += attr[i2 * AD + d] * Wa[d];
        }
        const float aw1 = 1.f / (1.f + __expf(-d1));
        const float aw2 = 1.f / (1.f + __expf(-d2));
        const float mult = 0.9f + 0.2f * (G1 * aw1 + G2 * aw2);
        const float c1 = G1 * mult, c2 = G2 * mult;
        const int gt = t0 + t;
        // bucket by unordered pair; keep coefficient attached to its schema
        int lo, hi; float clo, chi;
        if (i1 < i2) { lo = i1; hi = i2; clo = c1; chi = c2; }
        else         { lo = i2; hi = i1; clo = c2; chi = c1; }
        const int p = lo * NS + hi;
        const int pos = atomicAdd(cnt + p, 1);
        if (pos < CAPP) {
            tok_list[p * CAPP + pos] = gt;
            cfa_list[p * CAPP + pos] = clo;
            cfb_list[p * CAPP + pos] = chi;
        }
    }
}

// ---------------- fused A+B helper: y[w*4+r][k] = cf * (h[tok,:] @ UT[s][k,:]) ----------------
// Wave = 4 tokens, K split across lanes, h register-dbuf, UT lane-coalesced (L2).
// Butterfly reduce -> lane L holds y for (token w*4 + (L>>4), k = L&15); write to LDS.
// LDS region is private to the wave -> no barrier needed (same-wave DS ops are in-order).
__device__ __forceinline__ void y_phase(const float* __restrict__ h,
                                        const float* __restrict__ UTs,
                                        const int (&tok)[4], const float (&cf)[4],
                                        const int lane, float* __restrict__ yout)
{
    float vals[64];
    #pragma unroll
    for (int m = 0; m < 64; ++m) vals[m] = 0.f;

    float4 hA[4], hB[4];
    #pragma unroll
    for (int r = 0; r < 4; ++r)
        hA[r] = *(const float4*)(h + (size_t)tok[r] * HD + lane * 4);

    #pragma unroll 1
    for (int c = 0; c < 8; c += 2) {
        #pragma unroll
        for (int r = 0; r < 4; ++r)
            hB[r] = *(const float4*)(h + (size_t)tok[r] * HD + (c + 1) * 256 + lane * 4);
        #pragma unroll
        for (int kg = 0; kg < 4; ++kg) {
            #pragma unroll
            for (int q = 0; q < 4; ++q) {
                const float4 uv = *(const float4*)(UTs + (size_t)(kg * 4 + q) * HD + c * 256 + lane * 4);
                #pragma unroll
                for (int r = 0; r < 4; ++r)
                    vals[r * 16 + kg * 4 + q] += dot4(hA[r], uv);
            }
        }
        if (c < 6) {
            #pragma unroll
            for (int r = 0; r < 4; ++r)
                hA[r] = *(const float4*)(h + (size_t)tok[r] * HD + (c + 2) * 256 + lane * 4);
        }
        #pragma unroll
        for (int kg = 0; kg < 4; ++kg) {
            #pragma unroll
            for (int q = 0; q < 4; ++q) {
                const float4 uv = *(const float4*)(UTs + (size_t)(kg * 4 + q) * HD + (c + 1) * 256 + lane * 4);
                #pragma unroll
                for (int r = 0; r < 4; ++r)
                    vals[r * 16 + kg * 4 + q] += dot4(hB[r], uv);
            }
        }
    }

    // reduce 64 values across 64 lanes (pair-adjacent butterfly): lane L ends
    // holding full sum of value m = L  (m = r*16 + k).
    #pragma unroll
    for (int st = 0; st < 6; ++st) {
        const int d = 1 << st;
        const bool up = (lane & d) != 0;
        const int half = 32 >> st;
        #pragma unroll
        for (int i = 0; i < half; ++i) {
            const float lo = vals[2 * i], hi = vals[2 * i + 1];
            const float keep = up ? hi : lo, send = up ? lo : hi;
            vals[i] = keep + __shfl_xor(send, d, 64);
        }
    }
    const int rsel = lane >> 4;
    const float cfv = rsel == 0 ? cf[0] : rsel == 1 ? cf[1] : rsel == 2 ? cf[2] : cf[3];
    yout[lane] = vals[0] * cfv;
}

// ---------------- fused pass: per pair-bucket p=(sa,sb), chunk of 16 tokens ----------------
// A-phase twice (schemas sa, sb) -> y in LDS; B-phase: out[tok] = ya@V[sa] + yb@V[sb],
// single coalesced float4 store per element. Every token lives in exactly one bucket,
// so out is written exactly once: no RMW, no second pass, no race.
__global__ __launch_bounds__(256) void k_AB(
    const float* __restrict__ h, const int* __restrict__ cnt,
    const int* __restrict__ tok_list, const float* __restrict__ cfa_list,
    const float* __restrict__ cfb_list, const float* __restrict__ UT,
    const float* __restrict__ V, float* __restrict__ out)
{
    __shared__ __align__(16) float ya[256], yb[256];
    const int p = blockIdx.x;
    int count = cnt[p];
    if (count <= 0) return;                  // unused pair (incl. sa>=sb)
    if (count > CAPP) count = CAPP;
    const int sa = p >> 5, sb = p & (NS - 1);
    const int tid = threadIdx.x, w = tid >> 6, lane = tid & 63;
    const float* UTa = UT + (size_t)sa * RDIM * HD;
    const float* UTb = UT + (size_t)sb * RDIM * HD;
    const float* Va  = V  + (size_t)sa * RDIM * HD;
    const float* Vb  = V  + (size_t)sb * RDIM * HD;

    #pragma unroll 1
    for (int ci = blockIdx.y; ci * 16 < count; ci += gridDim.y) {
        int tok[4]; float cfa[4], cfb[4]; bool act[4];
        #pragma unroll
        for (int r = 0; r < 4; ++r) {
            const int idx = ci * 16 + w * 4 + r;
            act[r] = idx < count;
            tok[r] = act[r] ? tok_list[p * CAPP + idx] : 0;
            cfa[r] = act[r] ? cfa_list[p * CAPP + idx] : 0.f;
            cfb[r] = act[r] ? cfb_list[p * CAPP + idx] : 0.f;
        }

        // A-phases: wave-private LDS regions; same-wave DS ordering makes this
        // barrier-free (ya/yb[w*64..w*64+63] written and read only by wave w).
        y_phase(h, UTa, tok, cfa, lane, &ya[w * 64]);
        y_phase(h, UTb, tok, cfb, lane, &yb[w * 64]);

        // B-phase
        #pragma unroll 1
        for (int c = 0; c < 8; ++c) {
            float4 o[4];
            #pragma unroll
            for (int r = 0; r < 4; ++r) o[r] = make_float4(0.f, 0.f, 0.f, 0.f);

            #pragma unroll
            for (int kg = 0; kg < 4; ++kg) {
                float4 vv[4];
                #pragma unroll
                for (int q = 0; q < 4; ++q)
                    vv[q] = *(const float4*)(Va + (size_t)(kg * 4 + q) * HD + c * 256 + lane * 4);
                #pragma unroll
                for (int r = 0; r < 4; ++r) {
                    const float4 yv = *(const float4*)&ya[(w * 4 + r) * 16 + kg * 4];
                    fma4(o[r], yv.x, vv[0]); fma4(o[r], yv.y, vv[1]);
                    fma4(o[r], yv.z, vv[2]); fma4(o[r], yv.w, vv[3]);
                }
            }
            #pragma unroll
            for (int kg = 0; kg < 4; ++kg) {
                float4 vv[4];
                #pragma unroll
                for (int q = 0; q < 4; ++q)
                    vv[q] = *(const float4*)(Vb + (size_t)(kg * 4 + q) * HD + c * 256 + lane * 4);
                #pragma unroll
                for (int r = 0; r < 4; ++r) {
                    const float4 yv = *(const float4*)&yb[(w * 4 + r) * 16 + kg * 4];
                    fma4(o[r], yv.x, vv[0]); fma4(o[r], yv.y, vv[1]);
                    fma4(o[r], yv.z, vv[2]); fma4(o[r], yv.w, vv[3]);
                }
            }
            #pragma unroll
            for (int r = 0; r < 4; ++r)
                if (act[r])
                    *(float4*)(out + (size_t)tok[r] * HD + c * 256 + lane * 4) = o[r];
        }
    }
}

extern "C" void kernel_launch(void* const* d_in, const int* in_sizes, int n_in,
                              void* d_out, int out_size, void* d_ws, size_t ws_size,
                              hipStream_t stream)
{
    const float* h    = (const float*)d_in[0];
    const float* Wr   = (const float*)d_in[1];
    const float* U    = (const float*)d_in[2];
    const float* V    = (const float*)d_in[3];
    const float* attr = (const float*)d_in[4];
    const float* Wa   = (const float*)d_in[5];
    float* outp = (float*)d_out;

    char* ws = (char*)d_ws;
    int*   cnt      = (int*)ws;
    int*   tok_list = (int*)(ws + 4096);
    float* cfa_list = (float*)(ws + 4096 + (size_t)NPAIR * CAPP * 4);
    float* cfb_list = (float*)(ws + 4096 + (size_t)2 * NPAIR * CAPP * 4);
    float* UT       = (float*)(ws + 4096 + (size_t)3 * NPAIR * CAPP * 4);

    hipLaunchKernelGGL(k_prep,   dim3(NS * 8 + 1), dim3(256), 0, stream, U, cnt, UT);
    hipLaunchKernelGGL(k_router, dim3(BT / 8),     dim3(256), 0, stream,
                       h, Wr, attr, Wa, cnt, tok_list, cfa_list, cfb_list);
    hipLaunchKernelGGL(k_AB,     dim3(NPAIR, 2),   dim3(256), 0, stream,
                       h, cnt, tok_list, cfa_list, cfb_list, UT, V, outp);
}